// Round 7
// baseline (943.927 us; speedup 1.0000x reference)
//
#include <hip/hip_runtime.h>
#include <hip/hip_bf16.h>

typedef __hip_bfloat16 bf16;
typedef __attribute__((ext_vector_type(8))) short short8;
typedef __attribute__((ext_vector_type(8))) unsigned short ushort8v;
typedef __attribute__((ext_vector_type(4))) float floatx4;

#define NPIX 65536   // 256*256

__device__ __forceinline__ float b2f(bf16 v) { return __bfloat162float(v); }
__device__ __forceinline__ bf16 f2b(float v) { return __float2bfloat16(v); }
__device__ __forceinline__ short f2bs(float v) { bf16 t = __float2bfloat16(v); return *(short*)&t; }
__device__ __forceinline__ float us2f(unsigned short u) {
  union { unsigned int i; float f; } t; t.i = ((unsigned int)u) << 16; return t.f;
}
__device__ __forceinline__ float gelu_f(float v) {
  return 0.5f * v * (1.f + erff(v * 0.7071067811865476f));
}

// ---- workspace layout (bytes) — total ~24.1 MiB ----
#define OFF_QKV 0u            // bf16 [192, NPIX] per-batch staging
#define OFF_KV  25165824u     // fp32 [2,8,72,8]
#define OFF_KS  25202688u     // fp32 [2,8,72]

__global__ void k_zero(float* __restrict__ p, int n) {
  int i = blockIdx.x * 256 + threadIdx.x;
  if (i < n) p[i] = 0.f;
}

// qkv 1x1 conv + ReLU on q,k. Grid (256, 3): y selects q/k/v section. Thread = pixel.
__global__ __launch_bounds__(256) void k_qkv(const float* __restrict__ x,
                                             const float* __restrict__ qkv_w,
                                             const float* __restrict__ qkv_b,
                                             bf16* __restrict__ qkv, int b) {
  int n = blockIdx.x * 256 + threadIdx.x;
  int sec = blockIdx.y;                      // 0=q, 1=k, 2=v
  const float* xp = x + ((size_t)b << 22) + n;
  float xv[64];
#pragma unroll
  for (int ci = 0; ci < 64; ++ci) xv[ci] = xp[(size_t)ci << 16];
  const float* w = qkv_w + sec * 64 * 64;    // [64][64] slice
  const float* bias = qkv_b + sec * 64;
  bf16* op = qkv + ((size_t)(sec * 64) << 16) + n;
  for (int co = 0; co < 64; ++co) {
    float acc = bias[co];
    const float* wr = w + co * 64;
#pragma unroll
    for (int ci = 0; ci < 64; ++ci) acc = fmaf(xv[ci], wr[ci], acc);
    if (sec < 2) acc = fmaxf(acc, 0.f);
    op[(size_t)co << 16] = f2b(acc);
  }
}

// Attention stats v3: kv[b,h,d,e] = sum_n k_c(n+off_p)*v_e(n), ksum[b,h,d] = sum_n k.
// Lane = (px-group g = (ln>>3)&7, e = ln&7). Each lane: 8 px via 16B loads, one e-plane.
// acc[9] + ks[9] only -> tiny butterfly tail (3 xor steps over g).
// Grid: dim3(32 chunks of 8 rows, 8 c, 8 h); 256 thr (4 waves, wave = quarter-row).
__global__ __launch_bounds__(256) void k_stats(const bf16* __restrict__ qkv,
                                               float* __restrict__ kv,
                                               float* __restrict__ ksum, int b) {
  int tid = threadIdx.x;
  int ln = tid & 63, wv = tid >> 6;
  int e = ln & 7, g = (ln >> 3) & 7;
  int chunk = blockIdx.x, c = blockIdx.y, h = blockIdx.z;
  const bf16* kp = qkv + ((size_t)(64 + h * 8 + c) << 16);
  const bf16* vp = qkv + ((size_t)(128 + h * 8 + e) << 16);
  int x0 = wv * 64 + g * 8;                  // [0, 248], multiple of 8

  float acc[9], ks[9];
#pragma unroll
  for (int p = 0; p < 9; ++p) { acc[p] = 0.f; ks[p] = 0.f; }

  for (int it = 0; it < 8; ++it) {
    int row = (chunk << 3) + it;
    // v: 8 px, one 16B load
    ushort8v vv = *(const ushort8v*)((const unsigned short*)vp + row * 256 + x0);
    float vf[8];
#pragma unroll
    for (int i = 0; i < 8; ++i) vf[i] = us2f(vv[i]);
    // k window: rows row-1..row+1, x in [x0-1, x0+8]  (W[r][j] = k at x0-1+j)
    float W[3][10];
#pragma unroll
    for (int r = 0; r < 3; ++r) {
#pragma unroll
      for (int j = 0; j < 10; ++j) W[r][j] = 0.f;
      int yy = row + r - 1;
      if ((unsigned)yy < 256u) {
        const unsigned short* krow = (const unsigned short*)kp + yy * 256;
        ushort8v m = *(const ushort8v*)(krow + x0);
#pragma unroll
        for (int j = 0; j < 8; ++j) W[r][j + 1] = us2f(m[j]);
        if (x0 > 0) W[r][0] = us2f(krow[x0 - 1]);
        if (x0 < 248) W[r][9] = us2f(krow[x0 + 8]);
      }
    }
    // taps: p = r*3 + t; px i uses window index i+t
#pragma unroll
    for (int r = 0; r < 3; ++r)
#pragma unroll
      for (int t = 0; t < 3; ++t) {
        int p = r * 3 + t;
#pragma unroll
        for (int i = 0; i < 8; ++i) {
          acc[p] = fmaf(W[r][i + t], vf[i], acc[p]);
          ks[p] += W[r][i + t];
        }
      }
  }

  // reduce across px-group dim (xor masks 8,16,32); then g==0 lanes commit.
#pragma unroll
  for (int p = 0; p < 9; ++p) {
#pragma unroll
    for (int s = 8; s < 64; s <<= 1) {
      acc[p] += __shfl_xor(acc[p], s, 64);
      ks[p] += __shfl_xor(ks[p], s, 64);
    }
  }
  if (g == 0) {
    int dbase = (b * 8 + h) * 72 + c * 9;
#pragma unroll
    for (int p = 0; p < 9; ++p) {
      atomicAdd(&kv[((dbase + p) << 3) + e], acc[p]);
      if (e == 0) atomicAdd(&ksum[dbase + p], ks[p]);
    }
  }
}

// o[h*8+e, n] = (sum_d q[n,d]*kv[d,e]) / (sum_d q[n,d]*ksum[d] + eps); o -> v planes.
__global__ __launch_bounds__(256) void k_apply(bf16* __restrict__ qkv,
                                               const float* __restrict__ kv,
                                               const float* __restrict__ ksum, int b) {
  int blk = blockIdx.x;
  int chunk = blk & 255, h = blk >> 8;
  int n = (chunk << 8) + threadIdx.x;
  int y = n >> 8, xx = n & 255;
  const float* kvb = kv + (size_t)((b * 8 + h) * 72) * 8;
  const float* ksb = ksum + (b * 8 + h) * 72;
  float num[8] = {0.f, 0.f, 0.f, 0.f, 0.f, 0.f, 0.f, 0.f};
  float den = 0.f;
  for (int c = 0; c < 8; ++c) {
    const bf16* qp = qkv + ((size_t)(h * 8 + c) << 16);
#pragma unroll
    for (int p = 0; p < 9; ++p) {
      int yy = y + p / 3 - 1, xc = xx + p % 3 - 1;
      float qv = 0.f;
      if ((unsigned)yy < 256u && (unsigned)xc < 256u) qv = b2f(qp[yy * 256 + xc]);
      int d = c * 9 + p;
      den = fmaf(qv, ksb[d], den);
#pragma unroll
      for (int e = 0; e < 8; ++e) num[e] = fmaf(qv, kvb[d * 8 + e], num[e]);
    }
  }
  float inv = 1.f / (den + 1e-6f);
#pragma unroll
  for (int e = 0; e < 8; ++e)
    qkv[((size_t)(128 + h * 8 + e) << 16) + n] = f2b(num[e] * inv);
}

// proj 3x3 conv as implicit GEMM via MFMA 16x16x32 bf16.
__global__ __launch_bounds__(256) void k_proj_mfma(const bf16* __restrict__ qkv,
                                                   const float* __restrict__ proj_w,
                                                   const float* __restrict__ proj_b,
                                                   const float* __restrict__ x,
                                                   float* __restrict__ out, int b) {
  __shared__ __align__(16) bf16 tile[3 * 130 * 72];
  int tid = threadIdx.x;
  int wv = tid >> 6, ln = tid & 63;
  int half = blockIdx.x, y = blockIdx.y;
  int x0 = half << 7;

  for (int pr = wv; pr < 192; pr += 4) {      // pr = dy*64 + ci
    int dy = pr >> 6, ci = pr & 63;
    int gy = y + dy - 1;
    const bf16* src = qkv + ((size_t)(128 + ci) << 16) + gy * 256;
    bool rowok = (unsigned)gy < 256u;
    for (int xl = ln; xl < 130; xl += 64) {
      int gx = x0 - 1 + xl;
      float v = 0.f;
      if (rowok && (unsigned)gx < 256u) v = b2f(src[gx]);
      tile[(dy * 130 + xl) * 72 + ci] = f2b(v);
    }
  }

  int m = ln & 15, quad = ln >> 4;
  int co = wv * 16 + m;
  short8 afrag[18];
#pragma unroll
  for (int s = 0; s < 18; ++s) {
    int p = s >> 1;
    int ci0 = (s & 1) * 32 + quad * 8;
    short8 af;
#pragma unroll
    for (int j = 0; j < 8; ++j)
      af[j] = f2bs(proj_w[(size_t)(co * 64 + ci0 + j) * 9 + p]);
    afrag[s] = af;
  }
  __syncthreads();

  floatx4 acc[8];
#pragma unroll
  for (int nt = 0; nt < 8; ++nt) acc[nt] = (floatx4){0.f, 0.f, 0.f, 0.f};
  int col = ln & 15;
#pragma unroll
  for (int s = 0; s < 18; ++s) {
    int p = s >> 1;
    int dy = p / 3, dx = p % 3;
    int ci_sub = (s & 1) * 32 + quad * 8;
    int base = (dy * 130 + col + dx) * 72 + ci_sub;
#pragma unroll
    for (int nt = 0; nt < 8; ++nt) {
      short8 bfrag = *(const short8*)&tile[base + nt * 16 * 72];
      acc[nt] = __builtin_amdgcn_mfma_f32_16x16x32_bf16(afrag[s], bfrag, acc[nt], 0, 0, 0);
    }
  }

  float bias4[4];
#pragma unroll
  for (int r = 0; r < 4; ++r) bias4[r] = proj_b[wv * 16 + quad * 4 + r];
#pragma unroll
  for (int nt = 0; nt < 8; ++nt) {
    int gx = x0 + nt * 16 + col;
#pragma unroll
    for (int r = 0; r < 4; ++r) {
      int co_r = wv * 16 + quad * 4 + r;
      size_t idx = ((size_t)(b * 64 + co_r) << 16) + (y << 8) + gx;
      out[idx] = x[idx] + bias4[r] + acc[nt][r];
    }
  }
}

// ffn1: 1x1 conv on x1 (fp32, in d_out) + exact GELU -> h1 in q planes. Thread = pixel.
__global__ __launch_bounds__(256) void k_ffn1(const float* __restrict__ out,
                                              const float* __restrict__ w1,
                                              const float* __restrict__ b1,
                                              bf16* __restrict__ qkv, int b) {
  int n = blockIdx.x * 256 + threadIdx.x;
  float xv[64];
  const float* xp = out + ((size_t)b << 22) + n;
#pragma unroll
  for (int ci = 0; ci < 64; ++ci) xv[ci] = xp[(size_t)ci << 16];
  for (int co = 0; co < 64; ++co) {
    float acc = b1[co];
    const float* wr = w1 + co * 64;
#pragma unroll
    for (int ci = 0; ci < 64; ++ci) acc = fmaf(xv[ci], wr[ci], acc);
    qkv[((size_t)co << 16) + n] = f2b(gelu_f(acc));
  }
}

// depthwise 3x3 + GELU: h1 (q planes) -> h2 (k planes). Thread = element.
__global__ __launch_bounds__(256) void k_dw(bf16* __restrict__ qkv,
                                            const float* __restrict__ dw_w,
                                            const float* __restrict__ dw_b) {
  int gid = blockIdx.x * 256 + threadIdx.x;   // [0, 64*NPIX)
  int n = gid & 65535;
  int c = gid >> 16;
  int y = n >> 8, xx = n & 255;
  const bf16* ip = qkv + ((size_t)c << 16);
  float acc = dw_b[c];
#pragma unroll
  for (int p = 0; p < 9; ++p) {
    int yy = y + p / 3 - 1, xc = xx + p % 3 - 1;
    if ((unsigned)yy < 256u && (unsigned)xc < 256u)
      acc = fmaf(b2f(ip[yy * 256 + xc]), dw_w[c * 9 + p], acc);
  }
  qkv[((size_t)(64 + c) << 16) + n] = f2b(gelu_f(acc));
}

// ffn2: 1x1 conv on h2 (k planes) + residual x1 (d_out, element-wise in place, fp32).
__global__ __launch_bounds__(256) void k_ffn2(const bf16* __restrict__ qkv,
                                              const float* __restrict__ w2,
                                              const float* __restrict__ b2,
                                              float* __restrict__ out, int b) {
  int n = blockIdx.x * 256 + threadIdx.x;
  float xv[64];
  const bf16* xp = qkv + ((size_t)64 << 16) + n;
#pragma unroll
  for (int ci = 0; ci < 64; ++ci) xv[ci] = b2f(xp[(size_t)ci << 16]);
  for (int co = 0; co < 64; ++co) {
    float acc = b2[co];
    const float* wr = w2 + co * 64;
#pragma unroll
    for (int ci = 0; ci < 64; ++ci) acc = fmaf(xv[ci], wr[ci], acc);
    size_t idx = ((size_t)b << 22) + ((size_t)co << 16) + n;
    out[idx] = out[idx] + acc;
  }
}

extern "C" void kernel_launch(void* const* d_in, const int* in_sizes, int n_in,
                              void* d_out, int out_size, void* d_ws, size_t ws_size,
                              hipStream_t stream) {
  const float* x      = (const float*)d_in[0];
  const float* qkv_w  = (const float*)d_in[1];
  const float* qkv_b  = (const float*)d_in[2];
  const float* proj_w = (const float*)d_in[3];
  const float* proj_b = (const float*)d_in[4];
  const float* ffn1_w = (const float*)d_in[5];
  const float* ffn1_b = (const float*)d_in[6];
  const float* dw_w   = (const float*)d_in[7];
  const float* dw_b   = (const float*)d_in[8];
  const float* ffn2_w = (const float*)d_in[9];
  const float* ffn2_b = (const float*)d_in[10];
  float* out = (float*)d_out;

  char* ws = (char*)d_ws;
  bf16*  qkvb = (bf16*)(ws + OFF_QKV);
  float* kvb  = (float*)(ws + OFF_KV);
  float* ksb  = (float*)(ws + OFF_KS);

  k_zero<<<41, 256, 0, stream>>>(kvb, 10368);  // kv (9216) + ksum (1152), contiguous

  for (int b = 0; b < 2; ++b) {
    k_qkv<<<dim3(256, 3), 256, 0, stream>>>(x, qkv_w, qkv_b, qkvb, b);
    k_stats<<<dim3(32, 8, 8), 256, 0, stream>>>(qkvb, kvb, ksb, b);
    k_apply<<<2048, 256, 0, stream>>>(qkvb, kvb, ksb, b);
    k_proj_mfma<<<dim3(2, 256), 256, 0, stream>>>(qkvb, proj_w, proj_b, x, out, b);
    k_ffn1<<<256, 256, 0, stream>>>(out, ffn1_w, ffn1_b, qkvb, b);
    k_dw<<<16384, 256, 0, stream>>>(qkvb, dw_w, dw_b);
    k_ffn2<<<256, 256, 0, stream>>>(qkvb, ffn2_w, ffn2_b, out, b);
  }
}

// Round 8
// 808.917 us; speedup vs baseline: 1.1669x; 1.1669x over previous
//
#include <hip/hip_runtime.h>
#include <hip/hip_bf16.h>

typedef __hip_bfloat16 bf16;
typedef __attribute__((ext_vector_type(8))) short short8;
typedef __attribute__((ext_vector_type(4))) float floatx4;

#define NPIX 65536   // 256*256

__device__ __forceinline__ float b2f(bf16 v) { return __bfloat162float(v); }
__device__ __forceinline__ bf16 f2b(float v) { return __float2bfloat16(v); }
__device__ __forceinline__ short f2bs(float v) { bf16 t = __float2bfloat16(v); return *(short*)&t; }
__device__ __forceinline__ float us2f(unsigned short u) {
  union { unsigned int i; float f; } t; t.i = ((unsigned int)u) << 16; return t.f;
}
__device__ __forceinline__ float gelu_f(float v) {
  return 0.5f * v * (1.f + erff(v * 0.7071067811865476f));
}

// ---- workspace layout (bytes) — total ~24.1 MiB ----
#define OFF_QKV 0u            // bf16 [192, NPIX] per-batch staging
#define OFF_KV  25165824u     // fp32 [2,8,72,8]
#define OFF_KS  25202688u     // fp32 [2,8,72]

__global__ void k_zero(float* __restrict__ p, int n) {
  int i = blockIdx.x * 256 + threadIdx.x;
  if (i < n) p[i] = 0.f;
}

// qkv 1x1 conv + ReLU on q,k. Grid (256, 3): y selects q/k/v section. Thread = pixel.
__global__ __launch_bounds__(256) void k_qkv(const float* __restrict__ x,
                                             const float* __restrict__ qkv_w,
                                             const float* __restrict__ qkv_b,
                                             bf16* __restrict__ qkv, int b) {
  int n = blockIdx.x * 256 + threadIdx.x;
  int sec = blockIdx.y;                      // 0=q, 1=k, 2=v
  const float* xp = x + ((size_t)b << 22) + n;
  float xv[64];
#pragma unroll
  for (int ci = 0; ci < 64; ++ci) xv[ci] = xp[(size_t)ci << 16];
  const float* w = qkv_w + sec * 64 * 64;    // [64][64] slice
  const float* bias = qkv_b + sec * 64;
  bf16* op = qkv + ((size_t)(sec * 64) << 16) + n;
  for (int co = 0; co < 64; ++co) {
    float acc = bias[co];
    const float* wr = w + co * 64;
#pragma unroll
    for (int ci = 0; ci < 64; ++ci) acc = fmaf(xv[ci], wr[ci], acc);
    if (sec < 2) acc = fmaxf(acc, 0.f);
    op[(size_t)co << 16] = f2b(acc);
  }
}

__device__ __forceinline__ void loadrow3(const unsigned short* __restrict__ kp,
                                         int y, int x, float w[3]) {
  if ((unsigned)y < 256u) {
    const unsigned short* r = kp + y * 256;
    w[0] = (x > 0) ? us2f(r[x - 1]) : 0.f;
    w[1] = us2f(r[x]);
    w[2] = (x < 255) ? us2f(r[x + 1]) : 0.f;
  } else {
    w[0] = w[1] = w[2] = 0.f;
  }
}

__device__ __forceinline__ void loadv8(const unsigned short* __restrict__ vp,
                                       int y, int x, float vf[8]) {
#pragma unroll
  for (int e = 0; e < 8; ++e) vf[e] = us2f(vp[((size_t)e << 16) + y * 256 + x]);
}

// Attention stats v4: kv[b,h,d,e] = sum_n k_c(n+off_p)*v_e(n), ksum[b,h,d] = sum_n k.
// Round-5 structure (lane = x-column, 81 independent accumulators) + sliding k-window
// (row reuse: 17 -> 11 loads/iter) + explicit 1-iter prefetch + grid 1024.
// Grid: dim3(16 chunks of 16 rows, 8 c, 8 h); 256 thr; thread walks 16 rows at fixed x.
__global__ __launch_bounds__(256) void k_stats(const bf16* __restrict__ qkv,
                                               float* __restrict__ kv,
                                               float* __restrict__ ksum, int b) {
  int tid = threadIdx.x;                     // x-column
  int chunk = blockIdx.x, c = blockIdx.y, h = blockIdx.z;
  const unsigned short* kp = (const unsigned short*)qkv + (((size_t)(64 + h * 8 + c)) << 16);
  const unsigned short* vp = (const unsigned short*)qkv + (((size_t)(128 + h * 8)) << 16);
  int x = tid;
  int y0 = chunk << 4;

  float acc[9][8], ks[9];
#pragma unroll
  for (int p = 0; p < 9; ++p) {
    ks[p] = 0.f;
#pragma unroll
    for (int e = 0; e < 8; ++e) acc[p][e] = 0.f;
  }

  // pipeline state: wm1=row(y-1), w0=row(y), wp1=row(y+1), vf=v(y); knext=row(y+2), vnext=v(y+1)
  float wm1[3], w0[3], wp1[3], vf[8], knext[3], vnext[8];
  loadrow3(kp, y0 - 1, x, wm1);
  loadrow3(kp, y0, x, w0);
  loadrow3(kp, y0 + 1, x, wp1);
  loadv8(vp, y0, x, vf);
  loadrow3(kp, y0 + 2, x, knext);
  loadv8(vp, (y0 + 1 < 256) ? y0 + 1 : 255, x, vnext);

  for (int i = 0; i < 16; ++i) {
    int y = y0 + i;
    // compute current row
#pragma unroll
    for (int t = 0; t < 3; ++t) {
      ks[t] += wm1[t];
      ks[3 + t] += w0[t];
      ks[6 + t] += wp1[t];
#pragma unroll
      for (int e = 0; e < 8; ++e) {
        acc[t][e] = fmaf(wm1[t], vf[e], acc[t][e]);
        acc[3 + t][e] = fmaf(w0[t], vf[e], acc[3 + t][e]);
        acc[6 + t][e] = fmaf(wp1[t], vf[e], acc[6 + t][e]);
      }
    }
    // rotate + issue next loads (consumed next iteration)
#pragma unroll
    for (int t = 0; t < 3; ++t) { wm1[t] = w0[t]; w0[t] = wp1[t]; wp1[t] = knext[t]; }
#pragma unroll
    for (int e = 0; e < 8; ++e) vf[e] = vnext[e];
    loadrow3(kp, y + 3, x, knext);
    int yv = y + 2;
    loadv8(vp, (yv < 256) ? yv : 255, x, vnext);
  }

  // full 64-lane butterfly, then cross-wave merge via LDS, then atomics.
#pragma unroll
  for (int p = 0; p < 9; ++p) {
#pragma unroll
    for (int e = 0; e < 8; ++e)
#pragma unroll
      for (int s = 1; s < 64; s <<= 1) acc[p][e] += __shfl_xor(acc[p][e], s, 64);
#pragma unroll
    for (int s = 1; s < 64; s <<= 1) ks[p] += __shfl_xor(ks[p], s, 64);
  }
  __shared__ float red[4][81];
  int wv = tid >> 6, ln = tid & 63;
  if (ln == 0) {
#pragma unroll
    for (int p = 0; p < 9; ++p) {
#pragma unroll
      for (int e = 0; e < 8; ++e) red[wv][p * 8 + e] = acc[p][e];
      red[wv][72 + p] = ks[p];
    }
  }
  __syncthreads();
  if (tid < 81) {
    float s = red[0][tid] + red[1][tid] + red[2][tid] + red[3][tid];
    int dbase = (b * 8 + h) * 72 + c * 9;
    if (tid < 72) atomicAdd(&kv[((dbase + (tid >> 3)) << 3) + (tid & 7)], s);
    else atomicAdd(&ksum[dbase + (tid - 72)], s);
  }
}

// o[h*8+e, n] = (sum_d q[n,d]*kv[d,e]) / (sum_d q[n,d]*ksum[d] + eps); o -> v planes.
__global__ __launch_bounds__(256) void k_apply(bf16* __restrict__ qkv,
                                               const float* __restrict__ kv,
                                               const float* __restrict__ ksum, int b) {
  int blk = blockIdx.x;
  int chunk = blk & 255, h = blk >> 8;
  int n = (chunk << 8) + threadIdx.x;
  int y = n >> 8, xx = n & 255;
  const float* kvb = kv + (size_t)((b * 8 + h) * 72) * 8;
  const float* ksb = ksum + (b * 8 + h) * 72;
  float num[8] = {0.f, 0.f, 0.f, 0.f, 0.f, 0.f, 0.f, 0.f};
  float den = 0.f;
  for (int c = 0; c < 8; ++c) {
    const bf16* qp = qkv + ((size_t)(h * 8 + c) << 16);
#pragma unroll
    for (int p = 0; p < 9; ++p) {
      int yy = y + p / 3 - 1, xc = xx + p % 3 - 1;
      float qv = 0.f;
      if ((unsigned)yy < 256u && (unsigned)xc < 256u) qv = b2f(qp[yy * 256 + xc]);
      int d = c * 9 + p;
      den = fmaf(qv, ksb[d], den);
#pragma unroll
      for (int e = 0; e < 8; ++e) num[e] = fmaf(qv, kvb[d * 8 + e], num[e]);
    }
  }
  float inv = 1.f / (den + 1e-6f);
#pragma unroll
  for (int e = 0; e < 8; ++e)
    qkv[((size_t)(128 + h * 8 + e) << 16) + n] = f2b(num[e] * inv);
}

// proj 3x3 conv as implicit GEMM via MFMA 16x16x32 bf16.
__global__ __launch_bounds__(256) void k_proj_mfma(const bf16* __restrict__ qkv,
                                                   const float* __restrict__ proj_w,
                                                   const float* __restrict__ proj_b,
                                                   const float* __restrict__ x,
                                                   float* __restrict__ out, int b) {
  __shared__ __align__(16) bf16 tile[3 * 130 * 72];
  int tid = threadIdx.x;
  int wv = tid >> 6, ln = tid & 63;
  int half = blockIdx.x, y = blockIdx.y;
  int x0 = half << 7;

  for (int pr = wv; pr < 192; pr += 4) {      // pr = dy*64 + ci
    int dy = pr >> 6, ci = pr & 63;
    int gy = y + dy - 1;
    const bf16* src = qkv + ((size_t)(128 + ci) << 16) + gy * 256;
    bool rowok = (unsigned)gy < 256u;
    for (int xl = ln; xl < 130; xl += 64) {
      int gx = x0 - 1 + xl;
      float v = 0.f;
      if (rowok && (unsigned)gx < 256u) v = b2f(src[gx]);
      tile[(dy * 130 + xl) * 72 + ci] = f2b(v);
    }
  }

  int m = ln & 15, quad = ln >> 4;
  int co = wv * 16 + m;
  short8 afrag[18];
#pragma unroll
  for (int s = 0; s < 18; ++s) {
    int p = s >> 1;
    int ci0 = (s & 1) * 32 + quad * 8;
    short8 af;
#pragma unroll
    for (int j = 0; j < 8; ++j)
      af[j] = f2bs(proj_w[(size_t)(co * 64 + ci0 + j) * 9 + p]);
    afrag[s] = af;
  }
  __syncthreads();

  floatx4 acc[8];
#pragma unroll
  for (int nt = 0; nt < 8; ++nt) acc[nt] = (floatx4){0.f, 0.f, 0.f, 0.f};
  int col = ln & 15;
#pragma unroll
  for (int s = 0; s < 18; ++s) {
    int p = s >> 1;
    int dy = p / 3, dx = p % 3;
    int ci_sub = (s & 1) * 32 + quad * 8;
    int base = (dy * 130 + col + dx) * 72 + ci_sub;
#pragma unroll
    for (int nt = 0; nt < 8; ++nt) {
      short8 bfrag = *(const short8*)&tile[base + nt * 16 * 72];
      acc[nt] = __builtin_amdgcn_mfma_f32_16x16x32_bf16(afrag[s], bfrag, acc[nt], 0, 0, 0);
    }
  }

  float bias4[4];
#pragma unroll
  for (int r = 0; r < 4; ++r) bias4[r] = proj_b[wv * 16 + quad * 4 + r];
#pragma unroll
  for (int nt = 0; nt < 8; ++nt) {
    int gx = x0 + nt * 16 + col;
#pragma unroll
    for (int r = 0; r < 4; ++r) {
      int co_r = wv * 16 + quad * 4 + r;
      size_t idx = ((size_t)(b * 64 + co_r) << 16) + (y << 8) + gx;
      out[idx] = x[idx] + bias4[r] + acc[nt][r];
    }
  }
}

// ffn1: 1x1 conv on x1 (fp32, in d_out) + exact GELU -> h1 in q planes. Thread = pixel.
__global__ __launch_bounds__(256) void k_ffn1(const float* __restrict__ out,
                                              const float* __restrict__ w1,
                                              const float* __restrict__ b1,
                                              bf16* __restrict__ qkv, int b) {
  int n = blockIdx.x * 256 + threadIdx.x;
  float xv[64];
  const float* xp = out + ((size_t)b << 22) + n;
#pragma unroll
  for (int ci = 0; ci < 64; ++ci) xv[ci] = xp[(size_t)ci << 16];
  for (int co = 0; co < 64; ++co) {
    float acc = b1[co];
    const float* wr = w1 + co * 64;
#pragma unroll
    for (int ci = 0; ci < 64; ++ci) acc = fmaf(xv[ci], wr[ci], acc);
    qkv[((size_t)co << 16) + n] = f2b(gelu_f(acc));
  }
}

// depthwise 3x3 + GELU: h1 (q planes) -> h2 (k planes). Thread = element.
__global__ __launch_bounds__(256) void k_dw(bf16* __restrict__ qkv,
                                            const float* __restrict__ dw_w,
                                            const float* __restrict__ dw_b) {
  int gid = blockIdx.x * 256 + threadIdx.x;   // [0, 64*NPIX)
  int n = gid & 65535;
  int c = gid >> 16;
  int y = n >> 8, xx = n & 255;
  const bf16* ip = qkv + ((size_t)c << 16);
  float acc = dw_b[c];
#pragma unroll
  for (int p = 0; p < 9; ++p) {
    int yy = y + p / 3 - 1, xc = xx + p % 3 - 1;
    if ((unsigned)yy < 256u && (unsigned)xc < 256u)
      acc = fmaf(b2f(ip[yy * 256 + xc]), dw_w[c * 9 + p], acc);
  }
  qkv[((size_t)(64 + c) << 16) + n] = f2b(gelu_f(acc));
}

// ffn2: 1x1 conv on h2 (k planes) + residual x1 (d_out, element-wise in place, fp32).
__global__ __launch_bounds__(256) void k_ffn2(const bf16* __restrict__ qkv,
                                              const float* __restrict__ w2,
                                              const float* __restrict__ b2,
                                              float* __restrict__ out, int b) {
  int n = blockIdx.x * 256 + threadIdx.x;
  float xv[64];
  const bf16* xp = qkv + ((size_t)64 << 16) + n;
#pragma unroll
  for (int ci = 0; ci < 64; ++ci) xv[ci] = b2f(xp[(size_t)ci << 16]);
  for (int co = 0; co < 64; ++co) {
    float acc = b2[co];
    const float* wr = w2 + co * 64;
#pragma unroll
    for (int ci = 0; ci < 64; ++ci) acc = fmaf(xv[ci], wr[ci], acc);
    size_t idx = ((size_t)b << 22) + ((size_t)co << 16) + n;
    out[idx] = out[idx] + acc;
  }
}

extern "C" void kernel_launch(void* const* d_in, const int* in_sizes, int n_in,
                              void* d_out, int out_size, void* d_ws, size_t ws_size,
                              hipStream_t stream) {
  const float* x      = (const float*)d_in[0];
  const float* qkv_w  = (const float*)d_in[1];
  const float* qkv_b  = (const float*)d_in[2];
  const float* proj_w = (const float*)d_in[3];
  const float* proj_b = (const float*)d_in[4];
  const float* ffn1_w = (const float*)d_in[5];
  const float* ffn1_b = (const float*)d_in[6];
  const float* dw_w   = (const float*)d_in[7];
  const float* dw_b   = (const float*)d_in[8];
  const float* ffn2_w = (const float*)d_in[9];
  const float* ffn2_b = (const float*)d_in[10];
  float* out = (float*)d_out;

  char* ws = (char*)d_ws;
  bf16*  qkvb = (bf16*)(ws + OFF_QKV);
  float* kvb  = (float*)(ws + OFF_KV);
  float* ksb  = (float*)(ws + OFF_KS);

  k_zero<<<41, 256, 0, stream>>>(kvb, 10368);  // kv (9216) + ksum (1152), contiguous

  for (int b = 0; b < 2; ++b) {
    k_qkv<<<dim3(256, 3), 256, 0, stream>>>(x, qkv_w, qkv_b, qkvb, b);
    k_stats<<<dim3(16, 8, 8), 256, 0, stream>>>(qkvb, kvb, ksb, b);
    k_apply<<<2048, 256, 0, stream>>>(qkvb, kvb, ksb, b);
    k_proj_mfma<<<dim3(2, 256), 256, 0, stream>>>(qkvb, proj_w, proj_b, x, out, b);
    k_ffn1<<<256, 256, 0, stream>>>(out, ffn1_w, ffn1_b, qkvb, b);
    k_dw<<<16384, 256, 0, stream>>>(qkvb, dw_w, dw_b);
    k_ffn2<<<256, 256, 0, stream>>>(qkvb, ffn2_w, ffn2_b, out, b);
  }
}

// Round 9
// 487.787 us; speedup vs baseline: 1.9351x; 1.6583x over previous
//
#include <hip/hip_runtime.h>
#include <hip/hip_bf16.h>

typedef __hip_bfloat16 bf16;
typedef __attribute__((ext_vector_type(8))) short short8;
typedef __attribute__((ext_vector_type(4))) short short4v;
typedef __attribute__((ext_vector_type(4))) float floatx4;

#define NPIX 65536   // 256*256

__device__ __forceinline__ float b2f(bf16 v) { return __bfloat162float(v); }
__device__ __forceinline__ bf16 f2b(float v) { return __float2bfloat16(v); }
__device__ __forceinline__ short f2bs(float v) { bf16 t = __float2bfloat16(v); return *(short*)&t; }
__device__ __forceinline__ float us2f(unsigned short u) {
  union { unsigned int i; float f; } t; t.i = ((unsigned int)u) << 16; return t.f;
}
__device__ __forceinline__ float gelu_f(float v) {
  return 0.5f * v * (1.f + erff(v * 0.7071067811865476f));
}

// ---- workspace layout (bytes) — total ~24.1 MiB ----
#define OFF_QKV 0u            // bf16 [192, NPIX] per-batch staging
#define OFF_KV  25165824u     // fp32 [2,8,72,8]
#define OFF_KS  25202688u     // fp32 [2,8,72]

__global__ void k_zero(float* __restrict__ p, int n) {
  int i = blockIdx.x * 256 + threadIdx.x;
  if (i < n) p[i] = 0.f;
}

// ============ shared MFMA-GEMM pieces (mappings verified by k_proj_mfma) ============
// tile: [128 px][72-padded ci] bf16; stage 64 ci from fp32 planes (cvt) or bf16 planes.

__device__ __forceinline__ void stage_f32(const float* __restrict__ src, bf16* tile) {
  // src: base of plane 0 at this block's n0. 256 thr; px = tid&127, chalf = tid>>7.
  int tid = threadIdx.x;
  int px = tid & 127, chalf = tid >> 7;
#pragma unroll
  for (int it = 0; it < 8; ++it) {
    int ci0 = it * 8 + chalf * 4;
    short4v w;
#pragma unroll
    for (int j = 0; j < 4; ++j) w[j] = f2bs(src[((size_t)(ci0 + j) << 16) + px]);
    *(short4v*)&tile[px * 72 + ci0] = w;
  }
}

__device__ __forceinline__ void stage_bf16(const bf16* __restrict__ src, bf16* tile) {
  int tid = threadIdx.x;
  int px = tid & 127, chalf = tid >> 7;
  const unsigned short* s = (const unsigned short*)src;
#pragma unroll
  for (int it = 0; it < 8; ++it) {
    int ci0 = it * 8 + chalf * 4;
    short4v w;
#pragma unroll
    for (int j = 0; j < 4; ++j) w[j] = (short)s[((size_t)(ci0 + j) << 16) + px];
    *(short4v*)&tile[px * 72 + ci0] = w;
  }
}

// ============ qkv 1x1 conv via MFMA: grid (512 n-tiles, 3 sec) ============
__global__ __launch_bounds__(256) void k_qkv_mfma(const float* __restrict__ x,
                                                  const float* __restrict__ qkv_w,
                                                  const float* __restrict__ qkv_b,
                                                  bf16* __restrict__ qkv, int b) {
  __shared__ __align__(16) bf16 tile[128 * 72];
  int tid = threadIdx.x;
  int wv = tid >> 6, ln = tid & 63;
  int n0 = blockIdx.x << 7, sec = blockIdx.y;
  stage_f32(x + ((size_t)b << 22) + n0, tile);

  int m = ln & 15, quad = ln >> 4;
  int co = wv * 16 + m;
  const float* w = qkv_w + sec * 4096;
  short8 afrag[2];
#pragma unroll
  for (int s = 0; s < 2; ++s) {
    short8 af;
#pragma unroll
    for (int j = 0; j < 8; ++j) af[j] = f2bs(w[co * 64 + s * 32 + quad * 8 + j]);
    afrag[s] = af;
  }
  __syncthreads();

  floatx4 acc[8];
#pragma unroll
  for (int nt = 0; nt < 8; ++nt) acc[nt] = (floatx4){0.f, 0.f, 0.f, 0.f};
#pragma unroll
  for (int s = 0; s < 2; ++s) {
    int base = m * 72 + s * 32 + quad * 8;
#pragma unroll
    for (int nt = 0; nt < 8; ++nt) {
      short8 bfrag = *(const short8*)&tile[base + nt * 16 * 72];
      acc[nt] = __builtin_amdgcn_mfma_f32_16x16x32_bf16(afrag[s], bfrag, acc[nt], 0, 0, 0);
    }
  }

  bool relu = (sec < 2);
#pragma unroll
  for (int r = 0; r < 4; ++r) {
    int co_r = wv * 16 + quad * 4 + r;
    float bias = qkv_b[sec * 64 + co_r];
    bf16* op = qkv + ((size_t)(sec * 64 + co_r) << 16) + n0;
#pragma unroll
    for (int nt = 0; nt < 8; ++nt) {
      float v = acc[nt][r] + bias;
      if (relu) v = fmaxf(v, 0.f);
      op[nt * 16 + m] = f2b(v);
    }
  }
}

// ============ ffn1 1x1 conv + GELU via MFMA: grid 512 ============
__global__ __launch_bounds__(256) void k_ffn1_mfma(const float* __restrict__ xin,
                                                   const float* __restrict__ w1,
                                                   const float* __restrict__ b1,
                                                   bf16* __restrict__ qkv, int b) {
  __shared__ __align__(16) bf16 tile[128 * 72];
  int tid = threadIdx.x;
  int wv = tid >> 6, ln = tid & 63;
  int n0 = blockIdx.x << 7;
  stage_f32(xin + ((size_t)b << 22) + n0, tile);

  int m = ln & 15, quad = ln >> 4;
  int co = wv * 16 + m;
  short8 afrag[2];
#pragma unroll
  for (int s = 0; s < 2; ++s) {
    short8 af;
#pragma unroll
    for (int j = 0; j < 8; ++j) af[j] = f2bs(w1[co * 64 + s * 32 + quad * 8 + j]);
    afrag[s] = af;
  }
  __syncthreads();

  floatx4 acc[8];
#pragma unroll
  for (int nt = 0; nt < 8; ++nt) acc[nt] = (floatx4){0.f, 0.f, 0.f, 0.f};
#pragma unroll
  for (int s = 0; s < 2; ++s) {
    int base = m * 72 + s * 32 + quad * 8;
#pragma unroll
    for (int nt = 0; nt < 8; ++nt) {
      short8 bfrag = *(const short8*)&tile[base + nt * 16 * 72];
      acc[nt] = __builtin_amdgcn_mfma_f32_16x16x32_bf16(afrag[s], bfrag, acc[nt], 0, 0, 0);
    }
  }

#pragma unroll
  for (int r = 0; r < 4; ++r) {
    int co_r = wv * 16 + quad * 4 + r;
    float bias = b1[co_r];
    bf16* op = qkv + ((size_t)co_r << 16) + n0;
#pragma unroll
    for (int nt = 0; nt < 8; ++nt)
      op[nt * 16 + m] = f2b(gelu_f(acc[nt][r] + bias));
  }
}

// ============ ffn2 1x1 conv + residual via MFMA: grid 512 ============
__global__ __launch_bounds__(256) void k_ffn2_mfma(const bf16* __restrict__ qkv,
                                                   const float* __restrict__ w2,
                                                   const float* __restrict__ b2,
                                                   float* __restrict__ out, int b) {
  __shared__ __align__(16) bf16 tile[128 * 72];
  int tid = threadIdx.x;
  int wv = tid >> 6, ln = tid & 63;
  int n0 = blockIdx.x << 7;
  stage_bf16(qkv + ((size_t)64 << 16) + n0, tile);   // h2 in k planes

  int m = ln & 15, quad = ln >> 4;
  int co = wv * 16 + m;
  short8 afrag[2];
#pragma unroll
  for (int s = 0; s < 2; ++s) {
    short8 af;
#pragma unroll
    for (int j = 0; j < 8; ++j) af[j] = f2bs(w2[co * 64 + s * 32 + quad * 8 + j]);
    afrag[s] = af;
  }
  __syncthreads();

  floatx4 acc[8];
#pragma unroll
  for (int nt = 0; nt < 8; ++nt) acc[nt] = (floatx4){0.f, 0.f, 0.f, 0.f};
#pragma unroll
  for (int s = 0; s < 2; ++s) {
    int base = m * 72 + s * 32 + quad * 8;
#pragma unroll
    for (int nt = 0; nt < 8; ++nt) {
      short8 bfrag = *(const short8*)&tile[base + nt * 16 * 72];
      acc[nt] = __builtin_amdgcn_mfma_f32_16x16x32_bf16(afrag[s], bfrag, acc[nt], 0, 0, 0);
    }
  }

#pragma unroll
  for (int r = 0; r < 4; ++r) {
    int co_r = wv * 16 + quad * 4 + r;
    float bias = b2[co_r];
    float* op = out + ((size_t)b << 22) + ((size_t)co_r << 16) + n0;
#pragma unroll
    for (int nt = 0; nt < 8; ++nt) {
      int i = nt * 16 + m;
      op[i] = op[i] + bias + acc[nt][r];
    }
  }
}

__device__ __forceinline__ void loadrow3(const unsigned short* __restrict__ kp,
                                         int y, int x, float w[3]) {
  if ((unsigned)y < 256u) {
    const unsigned short* r = kp + y * 256;
    w[0] = (x > 0) ? us2f(r[x - 1]) : 0.f;
    w[1] = us2f(r[x]);
    w[2] = (x < 255) ? us2f(r[x + 1]) : 0.f;
  } else {
    w[0] = w[1] = w[2] = 0.f;
  }
}

__device__ __forceinline__ void loadv8(const unsigned short* __restrict__ vp,
                                       int y, int x, float vf[8]) {
#pragma unroll
  for (int e = 0; e < 8; ++e) vf[e] = us2f(vp[((size_t)e << 16) + y * 256 + x]);
}

// Attention stats v4 (round-8 winner): sliding k-window + 1-iter prefetch.
__global__ __launch_bounds__(256) void k_stats(const bf16* __restrict__ qkv,
                                               float* __restrict__ kv,
                                               float* __restrict__ ksum, int b) {
  int tid = threadIdx.x;
  int chunk = blockIdx.x, c = blockIdx.y, h = blockIdx.z;
  const unsigned short* kp = (const unsigned short*)qkv + (((size_t)(64 + h * 8 + c)) << 16);
  const unsigned short* vp = (const unsigned short*)qkv + (((size_t)(128 + h * 8)) << 16);
  int x = tid;
  int y0 = chunk << 4;

  float acc[9][8], ks[9];
#pragma unroll
  for (int p = 0; p < 9; ++p) {
    ks[p] = 0.f;
#pragma unroll
    for (int e = 0; e < 8; ++e) acc[p][e] = 0.f;
  }

  float wm1[3], w0[3], wp1[3], vf[8], knext[3], vnext[8];
  loadrow3(kp, y0 - 1, x, wm1);
  loadrow3(kp, y0, x, w0);
  loadrow3(kp, y0 + 1, x, wp1);
  loadv8(vp, y0, x, vf);
  loadrow3(kp, y0 + 2, x, knext);
  loadv8(vp, (y0 + 1 < 256) ? y0 + 1 : 255, x, vnext);

  for (int i = 0; i < 16; ++i) {
    int y = y0 + i;
#pragma unroll
    for (int t = 0; t < 3; ++t) {
      ks[t] += wm1[t];
      ks[3 + t] += w0[t];
      ks[6 + t] += wp1[t];
#pragma unroll
      for (int e = 0; e < 8; ++e) {
        acc[t][e] = fmaf(wm1[t], vf[e], acc[t][e]);
        acc[3 + t][e] = fmaf(w0[t], vf[e], acc[3 + t][e]);
        acc[6 + t][e] = fmaf(wp1[t], vf[e], acc[6 + t][e]);
      }
    }
#pragma unroll
    for (int t = 0; t < 3; ++t) { wm1[t] = w0[t]; w0[t] = wp1[t]; wp1[t] = knext[t]; }
#pragma unroll
    for (int e = 0; e < 8; ++e) vf[e] = vnext[e];
    loadrow3(kp, y + 3, x, knext);
    int yv = y + 2;
    loadv8(vp, (yv < 256) ? yv : 255, x, vnext);
  }

#pragma unroll
  for (int p = 0; p < 9; ++p) {
#pragma unroll
    for (int e = 0; e < 8; ++e)
#pragma unroll
      for (int s = 1; s < 64; s <<= 1) acc[p][e] += __shfl_xor(acc[p][e], s, 64);
#pragma unroll
    for (int s = 1; s < 64; s <<= 1) ks[p] += __shfl_xor(ks[p], s, 64);
  }
  __shared__ float red[4][81];
  int wv = tid >> 6, ln = tid & 63;
  if (ln == 0) {
#pragma unroll
    for (int p = 0; p < 9; ++p) {
#pragma unroll
      for (int e = 0; e < 8; ++e) red[wv][p * 8 + e] = acc[p][e];
      red[wv][72 + p] = ks[p];
    }
  }
  __syncthreads();
  if (tid < 81) {
    float s = red[0][tid] + red[1][tid] + red[2][tid] + red[3][tid];
    int dbase = (b * 8 + h) * 72 + c * 9;
    if (tid < 72) atomicAdd(&kv[((dbase + (tid >> 3)) << 3) + (tid & 7)], s);
    else atomicAdd(&ksum[dbase + (tid - 72)], s);
  }
}

// o[h*8+e, n] = (sum_d q[n,d]*kv[d,e]) / (sum_d q[n,d]*ksum[d] + eps); o -> v planes.
__global__ __launch_bounds__(256) void k_apply(bf16* __restrict__ qkv,
                                               const float* __restrict__ kv,
                                               const float* __restrict__ ksum, int b) {
  int blk = blockIdx.x;
  int chunk = blk & 255, h = blk >> 8;
  int n = (chunk << 8) + threadIdx.x;
  int y = n >> 8, xx = n & 255;
  const float* kvb = kv + (size_t)((b * 8 + h) * 72) * 8;
  const float* ksb = ksum + (b * 8 + h) * 72;
  float num[8] = {0.f, 0.f, 0.f, 0.f, 0.f, 0.f, 0.f, 0.f};
  float den = 0.f;
  for (int c = 0; c < 8; ++c) {
    const bf16* qp = qkv + ((size_t)(h * 8 + c) << 16);
#pragma unroll
    for (int p = 0; p < 9; ++p) {
      int yy = y + p / 3 - 1, xc = xx + p % 3 - 1;
      float qv = 0.f;
      if ((unsigned)yy < 256u && (unsigned)xc < 256u) qv = b2f(qp[yy * 256 + xc]);
      int d = c * 9 + p;
      den = fmaf(qv, ksb[d], den);
#pragma unroll
      for (int e = 0; e < 8; ++e) num[e] = fmaf(qv, kvb[d * 8 + e], num[e]);
    }
  }
  float inv = 1.f / (den + 1e-6f);
#pragma unroll
  for (int e = 0; e < 8; ++e)
    qkv[((size_t)(128 + h * 8 + e) << 16) + n] = f2b(num[e] * inv);
}

// proj 3x3 conv as implicit GEMM via MFMA 16x16x32 bf16.
__global__ __launch_bounds__(256) void k_proj_mfma(const bf16* __restrict__ qkv,
                                                   const float* __restrict__ proj_w,
                                                   const float* __restrict__ proj_b,
                                                   const float* __restrict__ x,
                                                   float* __restrict__ out, int b) {
  __shared__ __align__(16) bf16 tile[3 * 130 * 72];
  int tid = threadIdx.x;
  int wv = tid >> 6, ln = tid & 63;
  int half = blockIdx.x, y = blockIdx.y;
  int x0 = half << 7;

  for (int pr = wv; pr < 192; pr += 4) {      // pr = dy*64 + ci
    int dy = pr >> 6, ci = pr & 63;
    int gy = y + dy - 1;
    const bf16* src = qkv + ((size_t)(128 + ci) << 16) + gy * 256;
    bool rowok = (unsigned)gy < 256u;
    for (int xl = ln; xl < 130; xl += 64) {
      int gx = x0 - 1 + xl;
      float v = 0.f;
      if (rowok && (unsigned)gx < 256u) v = b2f(src[gx]);
      tile[(dy * 130 + xl) * 72 + ci] = f2b(v);
    }
  }

  int m = ln & 15, quad = ln >> 4;
  int co = wv * 16 + m;
  short8 afrag[18];
#pragma unroll
  for (int s = 0; s < 18; ++s) {
    int p = s >> 1;
    int ci0 = (s & 1) * 32 + quad * 8;
    short8 af;
#pragma unroll
    for (int j = 0; j < 8; ++j)
      af[j] = f2bs(proj_w[(size_t)(co * 64 + ci0 + j) * 9 + p]);
    afrag[s] = af;
  }
  __syncthreads();

  floatx4 acc[8];
#pragma unroll
  for (int nt = 0; nt < 8; ++nt) acc[nt] = (floatx4){0.f, 0.f, 0.f, 0.f};
  int col = ln & 15;
#pragma unroll
  for (int s = 0; s < 18; ++s) {
    int p = s >> 1;
    int dy = p / 3, dx = p % 3;
    int ci_sub = (s & 1) * 32 + quad * 8;
    int base = (dy * 130 + col + dx) * 72 + ci_sub;
#pragma unroll
    for (int nt = 0; nt < 8; ++nt) {
      short8 bfrag = *(const short8*)&tile[base + nt * 16 * 72];
      acc[nt] = __builtin_amdgcn_mfma_f32_16x16x32_bf16(afrag[s], bfrag, acc[nt], 0, 0, 0);
    }
  }

  float bias4[4];
#pragma unroll
  for (int r = 0; r < 4; ++r) bias4[r] = proj_b[wv * 16 + quad * 4 + r];
#pragma unroll
  for (int nt = 0; nt < 8; ++nt) {
    int gx = x0 + nt * 16 + col;
#pragma unroll
    for (int r = 0; r < 4; ++r) {
      int co_r = wv * 16 + quad * 4 + r;
      size_t idx = ((size_t)(b * 64 + co_r) << 16) + (y << 8) + gx;
      out[idx] = x[idx] + bias4[r] + acc[nt][r];
    }
  }
}

// depthwise 3x3 + GELU: h1 (q planes) -> h2 (k planes). Thread = element.
__global__ __launch_bounds__(256) void k_dw(bf16* __restrict__ qkv,
                                            const float* __restrict__ dw_w,
                                            const float* __restrict__ dw_b) {
  int gid = blockIdx.x * 256 + threadIdx.x;   // [0, 64*NPIX)
  int n = gid & 65535;
  int c = gid >> 16;
  int y = n >> 8, xx = n & 255;
  const bf16* ip = qkv + ((size_t)c << 16);
  float acc = dw_b[c];
#pragma unroll
  for (int p = 0; p < 9; ++p) {
    int yy = y + p / 3 - 1, xc = xx + p % 3 - 1;
    if ((unsigned)yy < 256u && (unsigned)xc < 256u)
      acc = fmaf(b2f(ip[yy * 256 + xc]), dw_w[c * 9 + p], acc);
  }
  qkv[((size_t)(64 + c) << 16) + n] = f2b(gelu_f(acc));
}

extern "C" void kernel_launch(void* const* d_in, const int* in_sizes, int n_in,
                              void* d_out, int out_size, void* d_ws, size_t ws_size,
                              hipStream_t stream) {
  const float* x      = (const float*)d_in[0];
  const float* qkv_w  = (const float*)d_in[1];
  const float* qkv_b  = (const float*)d_in[2];
  const float* proj_w = (const float*)d_in[3];
  const float* proj_b = (const float*)d_in[4];
  const float* ffn1_w = (const float*)d_in[5];
  const float* ffn1_b = (const float*)d_in[6];
  const float* dw_w   = (const float*)d_in[7];
  const float* dw_b   = (const float*)d_in[8];
  const float* ffn2_w = (const float*)d_in[9];
  const float* ffn2_b = (const float*)d_in[10];
  float* out = (float*)d_out;

  char* ws = (char*)d_ws;
  bf16*  qkvb = (bf16*)(ws + OFF_QKV);
  float* kvb  = (float*)(ws + OFF_KV);
  float* ksb  = (float*)(ws + OFF_KS);

  k_zero<<<41, 256, 0, stream>>>(kvb, 10368);  // kv (9216) + ksum (1152), contiguous

  for (int b = 0; b < 2; ++b) {
    k_qkv_mfma<<<dim3(512, 3), 256, 0, stream>>>(x, qkv_w, qkv_b, qkvb, b);
    k_stats<<<dim3(16, 8, 8), 256, 0, stream>>>(qkvb, kvb, ksb, b);
    k_apply<<<2048, 256, 0, stream>>>(qkvb, kvb, ksb, b);
    k_proj_mfma<<<dim3(2, 256), 256, 0, stream>>>(qkvb, proj_w, proj_b, x, out, b);
    k_ffn1_mfma<<<512, 256, 0, stream>>>(out, ffn1_w, ffn1_b, qkvb, b);
    k_dw<<<16384, 256, 0, stream>>>(qkvb, dw_w, dw_b);
    k_ffn2_mfma<<<512, 256, 0, stream>>>(qkvb, ffn2_w, ffn2_b, out, b);
  }
}

// Round 10
// 450.065 us; speedup vs baseline: 2.0973x; 1.0838x over previous
//
#include <hip/hip_runtime.h>
#include <hip/hip_bf16.h>

typedef __hip_bfloat16 bf16;
typedef __attribute__((ext_vector_type(8))) short short8;
typedef __attribute__((ext_vector_type(4))) short short4v;
typedef __attribute__((ext_vector_type(4))) float floatx4;

#define NPIX 65536   // 256*256

__device__ __forceinline__ float b2f(bf16 v) { return __bfloat162float(v); }
__device__ __forceinline__ bf16 f2b(float v) { return __float2bfloat16(v); }
__device__ __forceinline__ short f2bs(float v) { bf16 t = __float2bfloat16(v); return *(short*)&t; }
__device__ __forceinline__ float us2f(unsigned short u) {
  union { unsigned int i; float f; } t; t.i = ((unsigned int)u) << 16; return t.f;
}
__device__ __forceinline__ float gelu_f(float v) {
  return 0.5f * v * (1.f + erff(v * 0.7071067811865476f));
}

// ---- workspace layout (bytes) ----
#define OFF_QKV 0u            // bf16 [192, NPIX]: q planes 0..63, k 64..127;
                              //   region 128..191 holds o as PIXEL-MAJOR [NPIX][64]
#define OFF_KV  25165824u     // fp32 [2,8,72,8]
#define OFF_KS  25202688u     // fp32 [2,8,72]
#define OFF_WP  25207296u     // bf16 wpack[9][64co][64ci] = 73,728 B

__global__ void k_zero(float* __restrict__ p, int n) {
  int i = blockIdx.x * 256 + threadIdx.x;
  if (i < n) p[i] = 0.f;
}

// pack proj_w [co][ci][p] fp32 -> wpack[p][co][ci] bf16 (A-fragment b128 source)
__global__ void k_pack(const float* __restrict__ pw, bf16* __restrict__ wpack) {
  int i = blockIdx.x * 256 + threadIdx.x;   // [0, 36864)
  int p = i >> 12, rem = i & 4095;
  int co = rem >> 6, ci = rem & 63;
  wpack[i] = f2b(pw[(co * 64 + ci) * 9 + p]);
}

// ============ shared MFMA-GEMM staging ============
__device__ __forceinline__ void stage_f32(const float* __restrict__ src, bf16* tile) {
  int tid = threadIdx.x;
  int px = tid & 127, chalf = tid >> 7;
#pragma unroll
  for (int it = 0; it < 8; ++it) {
    int ci0 = it * 8 + chalf * 4;
    short4v w;
#pragma unroll
    for (int j = 0; j < 4; ++j) w[j] = f2bs(src[((size_t)(ci0 + j) << 16) + px]);
    *(short4v*)&tile[px * 72 + ci0] = w;
  }
}

__device__ __forceinline__ void stage_bf16(const bf16* __restrict__ src, bf16* tile) {
  int tid = threadIdx.x;
  int px = tid & 127, chalf = tid >> 7;
  const unsigned short* s = (const unsigned short*)src;
#pragma unroll
  for (int it = 0; it < 8; ++it) {
    int ci0 = it * 8 + chalf * 4;
    short4v w;
#pragma unroll
    for (int j = 0; j < 4; ++j) w[j] = (short)s[((size_t)(ci0 + j) << 16) + px];
    *(short4v*)&tile[px * 72 + ci0] = w;
  }
}

// ============ qkv 1x1 conv via MFMA: grid (512 n-tiles, 3 sec) ============
__global__ __launch_bounds__(256) void k_qkv_mfma(const float* __restrict__ x,
                                                  const float* __restrict__ qkv_w,
                                                  const float* __restrict__ qkv_b,
                                                  bf16* __restrict__ qkv, int b) {
  __shared__ __align__(16) bf16 tile[128 * 72];
  int tid = threadIdx.x;
  int wv = tid >> 6, ln = tid & 63;
  int n0 = blockIdx.x << 7, sec = blockIdx.y;
  stage_f32(x + ((size_t)b << 22) + n0, tile);

  int m = ln & 15, quad = ln >> 4;
  int co = wv * 16 + m;
  const float* w = qkv_w + sec * 4096;
  short8 afrag[2];
#pragma unroll
  for (int s = 0; s < 2; ++s) {
    short8 af;
#pragma unroll
    for (int j = 0; j < 8; ++j) af[j] = f2bs(w[co * 64 + s * 32 + quad * 8 + j]);
    afrag[s] = af;
  }
  __syncthreads();

  floatx4 acc[8];
#pragma unroll
  for (int nt = 0; nt < 8; ++nt) acc[nt] = (floatx4){0.f, 0.f, 0.f, 0.f};
#pragma unroll
  for (int s = 0; s < 2; ++s) {
    int base = m * 72 + s * 32 + quad * 8;
#pragma unroll
    for (int nt = 0; nt < 8; ++nt) {
      short8 bfrag = *(const short8*)&tile[base + nt * 16 * 72];
      acc[nt] = __builtin_amdgcn_mfma_f32_16x16x32_bf16(afrag[s], bfrag, acc[nt], 0, 0, 0);
    }
  }

  bool relu = (sec < 2);
#pragma unroll
  for (int r = 0; r < 4; ++r) {
    int co_r = wv * 16 + quad * 4 + r;
    float bias = qkv_b[sec * 64 + co_r];
    bf16* op = qkv + ((size_t)(sec * 64 + co_r) << 16) + n0;
#pragma unroll
    for (int nt = 0; nt < 8; ++nt) {
      float v = acc[nt][r] + bias;
      if (relu) v = fmaxf(v, 0.f);
      op[nt * 16 + m] = f2b(v);
    }
  }
}

// ============ ffn1 1x1 conv + GELU via MFMA: grid 512 ============
__global__ __launch_bounds__(256) void k_ffn1_mfma(const float* __restrict__ xin,
                                                   const float* __restrict__ w1,
                                                   const float* __restrict__ b1,
                                                   bf16* __restrict__ qkv, int b) {
  __shared__ __align__(16) bf16 tile[128 * 72];
  int tid = threadIdx.x;
  int wv = tid >> 6, ln = tid & 63;
  int n0 = blockIdx.x << 7;
  stage_f32(xin + ((size_t)b << 22) + n0, tile);

  int m = ln & 15, quad = ln >> 4;
  int co = wv * 16 + m;
  short8 afrag[2];
#pragma unroll
  for (int s = 0; s < 2; ++s) {
    short8 af;
#pragma unroll
    for (int j = 0; j < 8; ++j) af[j] = f2bs(w1[co * 64 + s * 32 + quad * 8 + j]);
    afrag[s] = af;
  }
  __syncthreads();

  floatx4 acc[8];
#pragma unroll
  for (int nt = 0; nt < 8; ++nt) acc[nt] = (floatx4){0.f, 0.f, 0.f, 0.f};
#pragma unroll
  for (int s = 0; s < 2; ++s) {
    int base = m * 72 + s * 32 + quad * 8;
#pragma unroll
    for (int nt = 0; nt < 8; ++nt) {
      short8 bfrag = *(const short8*)&tile[base + nt * 16 * 72];
      acc[nt] = __builtin_amdgcn_mfma_f32_16x16x32_bf16(afrag[s], bfrag, acc[nt], 0, 0, 0);
    }
  }

#pragma unroll
  for (int r = 0; r < 4; ++r) {
    int co_r = wv * 16 + quad * 4 + r;
    float bias = b1[co_r];
    bf16* op = qkv + ((size_t)co_r << 16) + n0;
#pragma unroll
    for (int nt = 0; nt < 8; ++nt)
      op[nt * 16 + m] = f2b(gelu_f(acc[nt][r] + bias));
  }
}

// ============ ffn2 1x1 conv + residual via MFMA: grid 512 ============
__global__ __launch_bounds__(256) void k_ffn2_mfma(const bf16* __restrict__ qkv,
                                                   const float* __restrict__ w2,
                                                   const float* __restrict__ b2,
                                                   float* __restrict__ out, int b) {
  __shared__ __align__(16) bf16 tile[128 * 72];
  int tid = threadIdx.x;
  int wv = tid >> 6, ln = tid & 63;
  int n0 = blockIdx.x << 7;
  stage_bf16(qkv + ((size_t)64 << 16) + n0, tile);   // h2 in k planes

  int m = ln & 15, quad = ln >> 4;
  int co = wv * 16 + m;
  short8 afrag[2];
#pragma unroll
  for (int s = 0; s < 2; ++s) {
    short8 af;
#pragma unroll
    for (int j = 0; j < 8; ++j) af[j] = f2bs(w2[co * 64 + s * 32 + quad * 8 + j]);
    afrag[s] = af;
  }
  __syncthreads();

  floatx4 acc[8];
#pragma unroll
  for (int nt = 0; nt < 8; ++nt) acc[nt] = (floatx4){0.f, 0.f, 0.f, 0.f};
#pragma unroll
  for (int s = 0; s < 2; ++s) {
    int base = m * 72 + s * 32 + quad * 8;
#pragma unroll
    for (int nt = 0; nt < 8; ++nt) {
      short8 bfrag = *(const short8*)&tile[base + nt * 16 * 72];
      acc[nt] = __builtin_amdgcn_mfma_f32_16x16x32_bf16(afrag[s], bfrag, acc[nt], 0, 0, 0);
    }
  }

#pragma unroll
  for (int r = 0; r < 4; ++r) {
    int co_r = wv * 16 + quad * 4 + r;
    float bias = b2[co_r];
    float* op = out + ((size_t)b << 22) + ((size_t)co_r << 16) + n0;
#pragma unroll
    for (int nt = 0; nt < 8; ++nt) {
      int i = nt * 16 + m;
      op[i] = op[i] + bias + acc[nt][r];
    }
  }
}

__device__ __forceinline__ void loadrow3(const unsigned short* __restrict__ kp,
                                         int y, int x, float w[3]) {
  if ((unsigned)y < 256u) {
    const unsigned short* r = kp + y * 256;
    w[0] = (x > 0) ? us2f(r[x - 1]) : 0.f;
    w[1] = us2f(r[x]);
    w[2] = (x < 255) ? us2f(r[x + 1]) : 0.f;
  } else {
    w[0] = w[1] = w[2] = 0.f;
  }
}

__device__ __forceinline__ void loadv8(const unsigned short* __restrict__ vp,
                                       int y, int x, float vf[8]) {
#pragma unroll
  for (int e = 0; e < 8; ++e) vf[e] = us2f(vp[((size_t)e << 16) + y * 256 + x]);
}

// Attention stats v4 (round-8 winner): sliding k-window + 1-iter prefetch.
__global__ __launch_bounds__(256) void k_stats(const bf16* __restrict__ qkv,
                                               float* __restrict__ kv,
                                               float* __restrict__ ksum, int b) {
  int tid = threadIdx.x;
  int chunk = blockIdx.x, c = blockIdx.y, h = blockIdx.z;
  const unsigned short* kp = (const unsigned short*)qkv + (((size_t)(64 + h * 8 + c)) << 16);
  const unsigned short* vp = (const unsigned short*)qkv + (((size_t)(128 + h * 8)) << 16);
  int x = tid;
  int y0 = chunk << 4;

  float acc[9][8], ks[9];
#pragma unroll
  for (int p = 0; p < 9; ++p) {
    ks[p] = 0.f;
#pragma unroll
    for (int e = 0; e < 8; ++e) acc[p][e] = 0.f;
  }

  float wm1[3], w0[3], wp1[3], vf[8], knext[3], vnext[8];
  loadrow3(kp, y0 - 1, x, wm1);
  loadrow3(kp, y0, x, w0);
  loadrow3(kp, y0 + 1, x, wp1);
  loadv8(vp, y0, x, vf);
  loadrow3(kp, y0 + 2, x, knext);
  loadv8(vp, (y0 + 1 < 256) ? y0 + 1 : 255, x, vnext);

  for (int i = 0; i < 16; ++i) {
    int y = y0 + i;
#pragma unroll
    for (int t = 0; t < 3; ++t) {
      ks[t] += wm1[t];
      ks[3 + t] += w0[t];
      ks[6 + t] += wp1[t];
#pragma unroll
      for (int e = 0; e < 8; ++e) {
        acc[t][e] = fmaf(wm1[t], vf[e], acc[t][e]);
        acc[3 + t][e] = fmaf(w0[t], vf[e], acc[3 + t][e]);
        acc[6 + t][e] = fmaf(wp1[t], vf[e], acc[6 + t][e]);
      }
    }
#pragma unroll
    for (int t = 0; t < 3; ++t) { wm1[t] = w0[t]; w0[t] = wp1[t]; wp1[t] = knext[t]; }
#pragma unroll
    for (int e = 0; e < 8; ++e) vf[e] = vnext[e];
    loadrow3(kp, y + 3, x, knext);
    int yv = y + 2;
    loadv8(vp, (yv < 256) ? yv : 255, x, vnext);
  }

#pragma unroll
  for (int p = 0; p < 9; ++p) {
#pragma unroll
    for (int e = 0; e < 8; ++e)
#pragma unroll
      for (int s = 1; s < 64; s <<= 1) acc[p][e] += __shfl_xor(acc[p][e], s, 64);
#pragma unroll
    for (int s = 1; s < 64; s <<= 1) ks[p] += __shfl_xor(ks[p], s, 64);
  }
  __shared__ float red[4][81];
  int wv = tid >> 6, ln = tid & 63;
  if (ln == 0) {
#pragma unroll
    for (int p = 0; p < 9; ++p) {
#pragma unroll
      for (int e = 0; e < 8; ++e) red[wv][p * 8 + e] = acc[p][e];
      red[wv][72 + p] = ks[p];
    }
  }
  __syncthreads();
  if (tid < 81) {
    float s = red[0][tid] + red[1][tid] + red[2][tid] + red[3][tid];
    int dbase = (b * 8 + h) * 72 + c * 9;
    if (tid < 72) atomicAdd(&kv[((dbase + (tid >> 3)) << 3) + (tid & 7)], s);
    else atomicAdd(&ksum[dbase + (tid - 72)], s);
  }
}

// o -> PIXEL-MAJOR opx[n][64]: one 16B store per thread (channels h*8..h*8+7).
__global__ __launch_bounds__(256) void k_apply(bf16* __restrict__ qkv,
                                               bf16* __restrict__ opx,
                                               const float* __restrict__ kv,
                                               const float* __restrict__ ksum, int b) {
  int blk = blockIdx.x;
  int chunk = blk & 255, h = blk >> 8;
  int n = (chunk << 8) + threadIdx.x;
  int y = n >> 8, xx = n & 255;
  const float* kvb = kv + (size_t)((b * 8 + h) * 72) * 8;
  const float* ksb = ksum + (b * 8 + h) * 72;
  float num[8] = {0.f, 0.f, 0.f, 0.f, 0.f, 0.f, 0.f, 0.f};
  float den = 0.f;
  for (int c = 0; c < 8; ++c) {
    const bf16* qp = qkv + ((size_t)(h * 8 + c) << 16);
#pragma unroll
    for (int p = 0; p < 9; ++p) {
      int yy = y + p / 3 - 1, xc = xx + p % 3 - 1;
      float qv = 0.f;
      if ((unsigned)yy < 256u && (unsigned)xc < 256u) qv = b2f(qp[yy * 256 + xc]);
      int d = c * 9 + p;
      den = fmaf(qv, ksb[d], den);
#pragma unroll
      for (int e = 0; e < 8; ++e) num[e] = fmaf(qv, kvb[d * 8 + e], num[e]);
    }
  }
  float inv = 1.f / (den + 1e-6f);
  short8 ov;
#pragma unroll
  for (int e = 0; e < 8; ++e) ov[e] = f2bs(num[e] * inv);
  *(short8*)&opx[((size_t)n << 6) + h * 8] = ov;
}

// proj 3x3 conv via MFMA, LDS-free: B-fragments loaded directly from pixel-major opx.
// Grid dim3(2, 256); 256 thr; wave wv -> co [16wv,16wv+16).
__global__ __launch_bounds__(256) void k_proj_mfma(const bf16* __restrict__ opx,
                                                   const bf16* __restrict__ wpack,
                                                   const float* __restrict__ proj_b,
                                                   const float* __restrict__ x,
                                                   float* __restrict__ out, int b) {
  int tid = threadIdx.x;
  int wv = tid >> 6, ln = tid & 63;
  int half = blockIdx.x, y = blockIdx.y;
  int x0 = half << 7;
  int m = ln & 15, quad = ln >> 4;
  int co = wv * 16 + m;

  short8 afrag[18];
#pragma unroll
  for (int s = 0; s < 18; ++s) {
    int p = s >> 1;
    int ci0 = (s & 1) * 32 + quad * 8;
    afrag[s] = *(const short8*)&wpack[(p * 64 + co) * 64 + ci0];
  }

  floatx4 acc[8];
#pragma unroll
  for (int nt = 0; nt < 8; ++nt) acc[nt] = (floatx4){0.f, 0.f, 0.f, 0.f};

#pragma unroll
  for (int s = 0; s < 18; ++s) {
    int p = s >> 1;
    int dy = p / 3 - 1, dx = p % 3 - 1;
    int ci0 = (s & 1) * 32 + quad * 8;
    int gy = y + dy;
    bool yok = (unsigned)gy < 256u;
#pragma unroll
    for (int nt = 0; nt < 8; ++nt) {
      int gx = x0 + nt * 16 + m + dx;
      bool ok = yok && (unsigned)gx < 256u;
      int px = ok ? ((gy << 8) + gx) : 0;
      short8 bfrag = *(const short8*)&opx[((size_t)px << 6) + ci0];
      if (!ok) {
        short8 z = {0, 0, 0, 0, 0, 0, 0, 0};
        bfrag = z;
      }
      acc[nt] = __builtin_amdgcn_mfma_f32_16x16x32_bf16(afrag[s], bfrag, acc[nt], 0, 0, 0);
    }
  }

  float bias4[4];
#pragma unroll
  for (int r = 0; r < 4; ++r) bias4[r] = proj_b[wv * 16 + quad * 4 + r];
#pragma unroll
  for (int nt = 0; nt < 8; ++nt) {
    int gx = x0 + nt * 16 + m;
#pragma unroll
    for (int r = 0; r < 4; ++r) {
      int co_r = wv * 16 + quad * 4 + r;
      size_t idx = ((size_t)(b * 64 + co_r) << 16) + (y << 8) + gx;
      out[idx] = x[idx] + bias4[r] + acc[nt][r];
    }
  }
}

// depthwise 3x3 + GELU: h1 (q planes) -> h2 (k planes). Thread = element.
__global__ __launch_bounds__(256) void k_dw(bf16* __restrict__ qkv,
                                            const float* __restrict__ dw_w,
                                            const float* __restrict__ dw_b) {
  int gid = blockIdx.x * 256 + threadIdx.x;   // [0, 64*NPIX)
  int n = gid & 65535;
  int c = gid >> 16;
  int y = n >> 8, xx = n & 255;
  const bf16* ip = qkv + ((size_t)c << 16);
  float acc = dw_b[c];
#pragma unroll
  for (int p = 0; p < 9; ++p) {
    int yy = y + p / 3 - 1, xc = xx + p % 3 - 1;
    if ((unsigned)yy < 256u && (unsigned)xc < 256u)
      acc = fmaf(b2f(ip[yy * 256 + xc]), dw_w[c * 9 + p], acc);
  }
  qkv[((size_t)(64 + c) << 16) + n] = f2b(gelu_f(acc));
}

extern "C" void kernel_launch(void* const* d_in, const int* in_sizes, int n_in,
                              void* d_out, int out_size, void* d_ws, size_t ws_size,
                              hipStream_t stream) {
  const float* x      = (const float*)d_in[0];
  const float* qkv_w  = (const float*)d_in[1];
  const float* qkv_b  = (const float*)d_in[2];
  const float* proj_w = (const float*)d_in[3];
  const float* proj_b = (const float*)d_in[4];
  const float* ffn1_w = (const float*)d_in[5];
  const float* ffn1_b = (const float*)d_in[6];
  const float* dw_w   = (const float*)d_in[7];
  const float* dw_b   = (const float*)d_in[8];
  const float* ffn2_w = (const float*)d_in[9];
  const float* ffn2_b = (const float*)d_in[10];
  float* out = (float*)d_out;

  char* ws = (char*)d_ws;
  bf16*  qkvb  = (bf16*)(ws + OFF_QKV);
  bf16*  opx   = qkvb + ((size_t)128 << 16);   // v region, pixel-major [NPIX][64]
  float* kvb   = (float*)(ws + OFF_KV);
  float* ksb   = (float*)(ws + OFF_KS);
  bf16*  wpack = (bf16*)(ws + OFF_WP);

  k_zero<<<41, 256, 0, stream>>>(kvb, 10368);  // kv (9216) + ksum (1152), contiguous
  k_pack<<<144, 256, 0, stream>>>(proj_w, wpack);

  for (int b = 0; b < 2; ++b) {
    k_qkv_mfma<<<dim3(512, 3), 256, 0, stream>>>(x, qkv_w, qkv_b, qkvb, b);
    k_stats<<<dim3(16, 8, 8), 256, 0, stream>>>(qkvb, kvb, ksb, b);
    k_apply<<<2048, 256, 0, stream>>>(qkvb, opx, kvb, ksb, b);
    k_proj_mfma<<<dim3(2, 256), 256, 0, stream>>>(opx, wpack, proj_b, x, out, b);
    k_ffn1_mfma<<<512, 256, 0, stream>>>(out, ffn1_w, ffn1_b, qkvb, b);
    k_dw<<<16384, 256, 0, stream>>>(qkvb, dw_w, dw_b);
    k_ffn2_mfma<<<512, 256, 0, stream>>>(qkvb, ffn2_w, ffn2_b, out, b);
  }
}